// Round 7
// baseline (682.114 us; speedup 1.0000x reference)
//
#include <hip/hip_runtime.h>
#include <stdint.h>

#define Bsz 4
#define Lseq 4096
#define Dm 1024
#define Hh 16
#define Wc 256
#define FFd 4096
#define NC 16
#define NTOK (Bsz * Lseq)   // 16384

typedef unsigned short u16;

__device__ __forceinline__ float bf2f(u16 u) {
  union { unsigned int i; float f; } v; v.i = ((unsigned int)u) << 16; return v.f;
}
__device__ __forceinline__ u16 f2bf(float f) {
  union { float f; unsigned int i; } v; v.f = f;
  unsigned int r = v.i + 0x7fffu + ((v.i >> 16) & 1u);
  return (u16)(r >> 16);
}
__device__ __forceinline__ unsigned int pack2bf(float a, float b) {
  union { float f; unsigned int u; } x, y; x.f = a; y.f = b;
  return ((x.u + 0x8000u) >> 16) | ((y.u + 0x8000u) & 0xffff0000u);
}

// ---------------- utility kernels ----------------
__global__ void cvt_f32_bf16(const float* __restrict__ in, u16* __restrict__ out, long n) {
  long i = ((long)blockIdx.x * blockDim.x + threadIdx.x) * 4;
  if (i >= n) return;
  float4 v = *(const float4*)(in + i);
  u16 o[4] = { f2bf(v.x), f2bf(v.y), f2bf(v.z), f2bf(v.w) };
  *(uint2*)(out + i) = *(const uint2*)o;
}

__global__ void transpose_f32_bf16(const float* __restrict__ in, u16* __restrict__ out,
                                   int R, int C) {
  __shared__ float tile[32][33];
  int tx = threadIdx.x & 31, ty = threadIdx.x >> 5;       // 32 x 8
  int r0 = blockIdx.y * 32, c0 = blockIdx.x * 32;
#pragma unroll
  for (int k = 0; k < 4; ++k)
    tile[ty + 8 * k][tx] = in[(size_t)(r0 + ty + 8 * k) * C + c0 + tx];
  __syncthreads();
#pragma unroll
  for (int k = 0; k < 4; ++k)
    out[(size_t)(c0 + ty + 8 * k) * R + r0 + tx] = f2bf(tile[tx][ty + 8 * k]);
}

// ---------------- GEMM: 256x256, BK=64, m201-faithful 4-phase/tile schedule ----
typedef __attribute__((ext_vector_type(8))) short s16x8;
typedef __attribute__((ext_vector_type(4))) float fx4;
typedef __attribute__((address_space(1))) unsigned int as1u;
typedef __attribute__((address_space(3))) unsigned int as3u;
typedef __attribute__((address_space(3))) const u16 l16c;

__device__ __forceinline__ void gll16(const void* g, void* l) {
  __builtin_amdgcn_global_load_lds((as1u*)g, (as3u*)l, 16, 0, 0);
}

#define DSR(dst, base, IMM)                                                 \
  asm volatile("ds_read_b128 %0, %1 offset:" IMM : "=v"(dst) : "v"(base))

__device__ __forceinline__ void swizzle_mn(int MB, int NB, int* mb, int* nb) {
  int flat = blockIdx.y * NB + blockIdx.x;
  if ((MB & 7) == 0) {
    int xcd = flat & 7;
    int j = flat >> 3;
    int rpx = MB >> 3;
    *nb = j / rpx;
    int rowin = j - *nb * rpx;
    *mb = (rowin << 3) | xcd;
  } else {
    *mb = blockIdx.y; *nb = blockIdx.x;
  }
}

#define MFMA_Q(MQ, NQ)                                                           \
  {                                                                              \
    _Pragma("unroll") for (int mt = 0; mt < 4; ++mt) {                           \
      _Pragma("unroll") for (int nt = 0; nt < 2; ++nt) {                         \
        acc[(MQ)*4 + mt][(NQ)*2 + nt] = __builtin_amdgcn_mfma_f32_16x16x32_bf16( \
            af[mt][0], bfr[NQ][nt][0], acc[(MQ)*4 + mt][(NQ)*2 + nt], 0, 0, 0);  \
        acc[(MQ)*4 + mt][(NQ)*2 + nt] = __builtin_amdgcn_mfma_f32_16x16x32_bf16( \
            af[mt][1], bfr[NQ][nt][1], acc[(MQ)*4 + mt][(NQ)*2 + nt], 0, 0, 0);  \
      }                                                                          \
    }                                                                            \
  }

#define WAIT_LGKM_FENCE()                                  \
  asm volatile("s_waitcnt lgkmcnt(0)" ::: "memory");       \
  __builtin_amdgcn_sched_barrier(0);

// A-fragment reads (bases toggled per buffer): row r = wr*128 + mq*64 + mt*16+lm
#define R_A_MQ0()                     \
  DSR(af[0][0], bA0, "0");            \
  DSR(af[0][1], bA1, "0");            \
  DSR(af[1][0], bA0, "2048");         \
  DSR(af[1][1], bA1, "2048");         \
  DSR(af[2][0], bA0, "4096");         \
  DSR(af[2][1], bA1, "4096");         \
  DSR(af[3][0], bA0, "6144");         \
  DSR(af[3][1], bA1, "6144");
#define R_A_MQ1()                     \
  DSR(af[0][0], bA0, "8192");         \
  DSR(af[0][1], bA1, "8192");         \
  DSR(af[1][0], bA0, "10240");        \
  DSR(af[1][1], bA1, "10240");        \
  DSR(af[2][0], bA0, "12288");        \
  DSR(af[2][1], bA1, "12288");        \
  DSR(af[3][0], bA0, "14336");        \
  DSR(af[3][1], bA1, "14336");
// B-fragment reads: row = wc*64 + nq*32 + nt*16 + lm
#define R_B_NQ0()                     \
  DSR(bfr[0][0][0], bB0, "0");        \
  DSR(bfr[0][0][1], bB1, "0");        \
  DSR(bfr[0][1][0], bB0, "2048");     \
  DSR(bfr[0][1][1], bB1, "2048");
#define R_B_NQ1()                     \
  DSR(bfr[1][0][0], bB0, "4096");     \
  DSR(bfr[1][0][1], bB1, "4096");     \
  DSR(bfr[1][1][0], bB0, "6144");     \
  DSR(bfr[1][1][1], bB1, "6144");

// C[M,N] = A[M,K](bf16,lda) * Bm[N,K](bf16)^T (+bias). 512 thr, 8 waves 2Mx4N,
// per-wave out 128x64. LDS: As[2]+Bs[2] = 128 KiB, 2 K-tile double buffer.
//
// Half-tile row-sets matched to read retirement:
//   A-h0 = rows {0-63,128-191}  (all waves' mq0)  -> dead after P1's lgkm+bar
//   A-h1 = rows {64-127,192-255}(mq1)             -> dead after P3
//   B-h0 = rows {wc*64+[0,32)}  (nq0)             -> dead after P1
//   B-h1 = rows {wc*64+32+[0,32)} (nq1)           -> dead after P2
// Stage schedule during tile t (1 half-tile = 2 gll/wave per phase):
//   P1: B-h1(t+1) -> buf^1   [region held t-1's B-h1, dead since t-1 P2]
//   P2: A-h0(t+2) -> buf     [A-h0(t) dead after t P1]
//   P3: B-h0(t+2) -> buf     [B-h0(t) dead after t P1]
//   P4: A-h1(t+2) -> buf     [A-h1(t) dead after t P3]
// vmcnt(6) at P4 only: outstanding = {A0,B0,A1}(t+2) -> tile t+1 fully landed
// before any wave enters t+1 P1. Reads at t+1 {P1:A0,B0; P2:B1; P3:A1} all hit
// landed data. Never drains to 0 in steady state (T4).
template <int RELU, int OUTBF16, int HASBIAS>
__global__ __launch_bounds__(512, 2) void gemm8p(const u16* A, int lda,
                                                 const u16* Bm,
                                                 const float* __restrict__ bias,
                                                 void* Cp,
                                                 int M, int N, int K) {
  __shared__ __attribute__((aligned(16))) u16 As[2][256 * 64];
  __shared__ __attribute__((aligned(16))) u16 Bs[2][256 * 64];
  int tid = threadIdx.x;
  int lane = tid & 63, wid = tid >> 6;
  int lm = lane & 15, quad = lane >> 4;
  int wr = wid >> 2, wc = wid & 3;
  int mb, nb;
  swizzle_mn(gridDim.y, gridDim.x, &mb, &nb);
  int m0 = mb * 256, n0 = nb * 256;
  const u16* Ag = A + (size_t)m0 * lda;
  const u16* Bg = Bm + (size_t)n0 * K;
  int NT = K >> 6;   // >= 3 for all call sites (16 or 64)

  // swizzled read chunk offsets: logical chunk (ks*4+quad) ^ (row&7); row&7==lm&7
  int off0 = (quad ^ (lm & 7)) << 3;
  int off1 = ((4 + quad) ^ (lm & 7)) << 3;
  unsigned ldsA = (unsigned)(size_t)(l16c*)(&As[0][0]);
  unsigned ldsB = (unsigned)(size_t)(l16c*)(&Bs[0][0]);
  unsigned baseA0 = ldsA + (unsigned)(((wr * 128 + lm) * 64 + off0) * 2);
  unsigned baseA1 = ldsA + (unsigned)(((wr * 128 + lm) * 64 + off1) * 2);
  unsigned baseB0 = ldsB + (unsigned)(((wc * 64 + lm) * 64 + off0) * 2);
  unsigned baseB1 = ldsB + (unsigned)(((wc * 64 + lm) * 64 + off1) * 2);

  // staging geometry: wave stages granules j0=2*wid, j1=2*wid+1 of each half-tile
  int j0 = wid * 2, j1 = wid * 2 + 1;
  int rA0a = (j0 < 8) ? j0 * 8 : 128 + (j0 - 8) * 8;   // A-h0 granule rows
  int rA0b = (j1 < 8) ? j1 * 8 : 128 + (j1 - 8) * 8;
  int rA1a = rA0a + 64, rA1b = rA0b + 64;              // A-h1
  int rB0a = (j0 >> 2) * 64 + (j0 & 3) * 8;            // B-h0
  int rB0b = (j1 >> 2) * 64 + (j1 & 3) * 8;
  int rB1a = rB0a + 32, rB1b = rB0b + 32;              // B-h1
  int lrow = lane >> 3;
  int gsw = ((lane & 7) ^ lrow) << 3;                  // source-side chunk XOR
  const u16* pA0a = Ag + (size_t)(rA0a + lrow) * lda + gsw;
  const u16* pA0b = Ag + (size_t)(rA0b + lrow) * lda + gsw;
  const u16* pA1a = Ag + (size_t)(rA1a + lrow) * lda + gsw;
  const u16* pA1b = Ag + (size_t)(rA1b + lrow) * lda + gsw;
  const u16* pB0a = Bg + (size_t)(rB0a + lrow) * K + gsw;
  const u16* pB0b = Bg + (size_t)(rB0b + lrow) * K + gsw;
  const u16* pB1a = Bg + (size_t)(rB1a + lrow) * K + gsw;
  const u16* pB1b = Bg + (size_t)(rB1b + lrow) * K + gsw;
  char* AsB = (char*)&As[0][0];
  char* BsB = (char*)&Bs[0][0];
  unsigned dA0a = (unsigned)rA0a * 128, dA0b = (unsigned)rA0b * 128;
  unsigned dA1a = (unsigned)rA1a * 128, dA1b = (unsigned)rA1b * 128;
  unsigned dB0a = (unsigned)rB0a * 128, dB0b = (unsigned)rB0b * 128;
  unsigned dB1a = (unsigned)rB1a * 128, dB1b = (unsigned)rB1b * 128;

  fx4 acc[8][4] = {};
  s16x8 af[4][2];
  s16x8 bfr[2][2][2];

  // ---- prologue: tile0 {A0,B0,B1,A1} @k=0 (buf0); tile1 {A0,B0,A1} @k=64 (buf1)
  gll16(pA0a, AsB + dA0a);  gll16(pA0b, AsB + dA0b);
  gll16(pB0a, BsB + dB0a);  gll16(pB0b, BsB + dB0b);
  gll16(pB1a, BsB + dB1a);  gll16(pB1b, BsB + dB1b);
  gll16(pA1a, AsB + dA1a);  gll16(pA1b, AsB + dA1b);
  gll16(pA0a + 64, AsB + 32768 + dA0a);  gll16(pA0b + 64, AsB + 32768 + dA0b);
  gll16(pB0a + 64, BsB + 32768 + dB0a);  gll16(pB0b + 64, BsB + 32768 + dB0b);
  gll16(pA1a + 64, AsB + 32768 + dA1a);  gll16(pA1b + 64, AsB + 32768 + dA1b);
  // advance persistent ptrs to first in-loop use: B1 serves t+1, others t+2
  pA0a += 128; pA0b += 128; pA1a += 128; pA1b += 128;
  pB0a += 128; pB0b += 128;
  pB1a += 64;  pB1b += 64;
  asm volatile("s_waitcnt vmcnt(6)" ::: "memory");   // tile0 fully landed
  __builtin_amdgcn_s_barrier();

  for (int s = 0; s < NT; ++s) {
    unsigned bsel = (unsigned)((s & 1) << 15);
    unsigned bA0 = baseA0 + bsel, bA1 = baseA1 + bsel;
    unsigned bB0 = baseB0 + bsel, bB1 = baseB1 + bsel;
    char* bufA = AsB + bsel;
    char* bufB = BsB + bsel;
    char* bufBn = BsB + (bsel ^ 32768);

    // ---- P1: reads A-mq0 + B-nq0 (12 ds); stage B-h1(t+1) -> buf^1
    R_A_MQ0();
    R_B_NQ0();
    if (s + 1 < NT) { gll16(pB1a, bufBn + dB1a); gll16(pB1b, bufBn + dB1b); }
    asm volatile("s_waitcnt lgkmcnt(8)" ::: "memory");
    __builtin_amdgcn_s_barrier();
    WAIT_LGKM_FENCE()
    __builtin_amdgcn_s_setprio(1);
    MFMA_Q(0, 0)
    __builtin_amdgcn_s_setprio(0);
    __builtin_amdgcn_s_barrier();

    // ---- P2: reads B-nq1 (4 ds); stage A-h0(t+2) -> buf
    R_B_NQ1();
    if (s + 2 < NT) { gll16(pA0a, bufA + dA0a); gll16(pA0b, bufA + dA0b); }
    __builtin_amdgcn_s_barrier();
    WAIT_LGKM_FENCE()
    __builtin_amdgcn_s_setprio(1);
    MFMA_Q(0, 1)
    __builtin_amdgcn_s_setprio(0);
    __builtin_amdgcn_s_barrier();

    // ---- P3: reads A-mq1 (8 ds); stage B-h0(t+2) -> buf
    R_A_MQ1();
    if (s + 2 < NT) { gll16(pB0a, bufB + dB0a); gll16(pB0b, bufB + dB0b); }
    __builtin_amdgcn_s_barrier();
    WAIT_LGKM_FENCE()
    __builtin_amdgcn_s_setprio(1);
    MFMA_Q(1, 1)
    __builtin_amdgcn_s_setprio(0);
    __builtin_amdgcn_s_barrier();

    // ---- P4: stage A-h1(t+2) -> buf; K-tile boundary vmcnt; MFMA (1,0)
    if (s + 2 < NT) {
      gll16(pA1a, bufA + dA1a); gll16(pA1b, bufA + dA1b);
      asm volatile("s_waitcnt vmcnt(6)" ::: "memory");
    } else {
      asm volatile("s_waitcnt vmcnt(0)" ::: "memory");
    }
    __builtin_amdgcn_s_barrier();
    __builtin_amdgcn_s_setprio(1);
    MFMA_Q(1, 0)
    __builtin_amdgcn_s_setprio(0);
    __builtin_amdgcn_s_barrier();

    pA0a += 64; pA0b += 64; pA1a += 64; pA1b += 64;
    pB0a += 64; pB0b += 64; pB1a += 64; pB1b += 64;
  }

  // epilogue
  float* Cf = (float*)Cp;
  u16* Ch = (u16*)Cp;
#pragma unroll
  for (int ai = 0; ai < 8; ++ai) {
#pragma unroll
    for (int bi = 0; bi < 4; ++bi) {
      int col = n0 + wc * 64 + (bi >> 1) * 32 + (bi & 1) * 16 + lm;
      float bv = HASBIAS ? bias[col] : 0.f;
#pragma unroll
      for (int r = 0; r < 4; ++r) {
        int row = m0 + wr * 128 + (ai >> 2) * 64 + (ai & 3) * 16 + quad * 4 + r;
        float v = acc[ai][bi][r] + bv;
        if (RELU) v = v > 0.f ? v : 0.f;
        if (OUTBF16) Ch[(size_t)row * N + col] = f2bf(v);
        else         Cf[(size_t)row * N + col] = v;
      }
    }
  }
}

// ---------------- MFMA flash attention ----------------
#define PADK 72
#define PADV 136
#define PADP 40
#define PADO 72

__global__ __launch_bounds__(256, 2) void attn_mfma(u16* qkv) {
  __shared__ __attribute__((aligned(16))) u16 lds[38400];   // 76.8 KB
  u16* Klds  = lds;                    // 128 x PADK = 9216
  u16* Vtlds = lds + 9216;             // 64 x PADV  = 8704

  int bid = blockIdx.x;
  int h = bid & (Hh - 1);
  int c = (bid >> 4) & (NC - 1);
  int b = bid >> 8;
  int tid = threadIdx.x, lane = tid & 63, w = tid >> 6;
  int lm = lane & 15, quad = lane >> 4;
  u16* Pw = lds + 17920 + w * 5120;

  size_t rowbase = (size_t)b * Lseq;

  s16x8 qf[4][2];
#pragma unroll
  for (int nt = 0; nt < 4; ++nt)
#pragma unroll
    for (int ks = 0; ks < 2; ++ks) {
      int qtok = c * Wc + w * 64 + nt * 16 + lm;
      qf[nt][ks] = *(const s16x8*)(qkv + (rowbase + qtok) * 3072 + h * 64 + ks * 32 + quad * 8);
    }

  fx4 acc_o[4][4] = {};
  float lsum[4] = {0.f, 0.f, 0.f, 0.f};

  int nph = (c > 0) ? 4 : 2;
  int t0  = (c > 0) ? (c - 1) * Wc : 0;

  for (int ph = 0; ph < nph; ++ph) {
    int kt0 = t0 + ph * 128;
    __syncthreads();

#pragma unroll
    for (int it = 0; it < 4; ++it) {
      int s = tid + it * 256;
      int row = s >> 3, off = (s & 7) * 8;
      uint4 kv = *(const uint4*)(qkv + (rowbase + kt0 + row) * 3072 + 1024 + h * 64 + off);
      *(uint4*)(Klds + row * PADK + off) = kv;
    }
    {
      int d = lane;
      int kb = w * 32;
      u16 tmp[32];
#pragma unroll
      for (int i = 0; i < 32; ++i)
        tmp[i] = qkv[(rowbase + kt0 + kb + i) * 3072 + 2048 + h * 64 + d];
#pragma unroll
      for (int i = 0; i < 4; ++i)
        *(uint4*)(Vtlds + d * PADV + kb + i * 8) = *(const uint4*)(tmp + i * 8);
    }
    __syncthreads();

#pragma unroll
    for (int kt = 0; kt < 4; ++kt) {
      u16* Pb = Pw + (kt & 1) * 2560;
      fx4 sa[2][4] = {};
#pragma unroll
      for (int ks = 0; ks < 2; ++ks) {
        s16x8 kf0 = *(const s16x8*)(Klds + (kt * 32 + lm) * PADK + ks * 32 + quad * 8);
        s16x8 kf1 = *(const s16x8*)(Klds + (kt * 32 + 16 + lm) * PADK + ks * 32 + quad * 8);
#pragma unroll
        for (int nt = 0; nt < 4; ++nt) {
          sa[0][nt] = __builtin_amdgcn_mfma_f32_16x16x32_bf16(kf0, qf[nt][ks], sa[0][nt], 0, 0, 0);
          sa[1][nt] = __builtin_amdgcn_mfma_f32_16x16x32_bf16(kf1, qf[nt][ks], sa[1][nt], 0, 0, 0);
        }
      }
#pragma unroll
      for (int mt = 0; mt < 2; ++mt)
#pragma unroll
        for (int nt = 0; nt < 4; ++nt) {
          float e0 = __expf(sa[mt][nt][0] * 0.125f);
          float e1 = __expf(sa[mt][nt][1] * 0.125f);
          float e2 = __expf(sa[mt][nt][2] * 0.125f);
          float e3 = __expf(sa[mt][nt][3] * 0.125f);
          lsum[nt] += (e0 + e1) + (e2 + e3);
          uint2 pk; pk.x = pack2bf(e0, e1); pk.y = pack2bf(e2, e3);
          *(uint2*)(Pb + (nt * 16 + lm) * PADP + mt * 16 + quad * 4) = pk;
        }
#pragma unroll
      for (int mt = 0; mt < 4; ++mt) {
        s16x8 vf = *(const s16x8*)(Vtlds + (mt * 16 + lm) * PADV + kt * 32 + quad * 8);
#pragma unroll
        for (int nt = 0; nt < 4; ++nt) {
          s16x8 pf = *(const s16x8*)(Pb + (nt * 16 + lm) * PADP + quad * 8);
          acc_o[mt][nt] = __builtin_amdgcn_mfma_f32_16x16x32_bf16(vf, pf, acc_o[mt][nt], 0, 0, 0);
        }
      }
    }
  }

#pragma unroll
  for (int nt = 0; nt < 4; ++nt) {
    float v = lsum[nt];
    v += __shfl_xor(v, 16, 64);
    v += __shfl_xor(v, 32, 64);
    lsum[nt] = 1.f / v;
  }

  __syncthreads();
  u16* Obuf = lds;
#pragma unroll
  for (int mt = 0; mt < 4; ++mt)
#pragma unroll
    for (int nt = 0; nt < 4; ++nt) {
      float inv = lsum[nt];
      uint2 pk;
      pk.x = pack2bf(acc_o[mt][nt][0] * inv, acc_o[mt][nt][1] * inv);
      pk.y = pack2bf(acc_o[mt][nt][2] * inv, acc_o[mt][nt][3] * inv);
      int q = nt * 16 + lm;
      *(uint2*)(Obuf + (w * 64 + q) * PADO + mt * 16 + quad * 4) = pk;
    }
  __syncthreads();
#pragma unroll
  for (int it = 0; it < 8; ++it) {
    int s = tid + it * 256;
    int row = s >> 3, chunk = s & 7;
    uint4 v = *(const uint4*)(Obuf + row * PADO + chunk * 8);
    *(uint4*)(qkv + (rowbase + c * Wc + row) * 3072 + h * 64 + chunk * 8) = v;
  }
}

// ---------------- layernorm variants ----------------
__device__ __forceinline__ void ln_core(float sx, float sy, float sz, float sw,
                                        const float* gamma, const float* beta, int tid,
                                        float* red, float4* outv) {
  float part = sx + sy + sz + sw;
#pragma unroll
  for (int off = 32; off > 0; off >>= 1) part += __shfl_down(part, off, 64);
  if ((tid & 63) == 0) red[tid >> 6] = part;
  __syncthreads();
  float mean = (red[0] + red[1] + red[2] + red[3]) * (1.f / 1024.f);
  __syncthreads();

  float dx = sx - mean, dy = sy - mean, dz = sz - mean, dw = sw - mean;
  float sq = dx * dx + dy * dy + dz * dz + dw * dw;
#pragma unroll
  for (int off = 32; off > 0; off >>= 1) sq += __shfl_down(sq, off, 64);
  if ((tid & 63) == 0) red[tid >> 6] = sq;
  __syncthreads();
  float var = (red[0] + red[1] + red[2] + red[3]) * (1.f / 1024.f);
  float rs = rsqrtf(var + 1e-6f);

  float4 g = *(const float4*)(gamma + tid * 4);
  float4 be = *(const float4*)(beta + tid * 4);
  outv->x = g.x * dx * rs + be.x;
  outv->y = g.y * dy * rs + be.y;
  outv->z = g.z * dz * rs + be.z;
  outv->w = g.w * dw * rs + be.w;
}

__global__ __launch_bounds__(256) void ln1_kernel(const float* __restrict__ r,
                                                  const float* __restrict__ dl,
                                                  const float* __restrict__ gamma,
                                                  const float* __restrict__ beta,
                                                  u16* __restrict__ outh) {
  __shared__ float red[4];
  int row = blockIdx.x, tid = threadIdx.x;
  size_t base = (size_t)row * Dm;
  float4 rv = *(const float4*)(r + base + tid * 4);
  float4 dv = *(const float4*)(dl + base + tid * 4);
  float4 o;
  ln_core(rv.x + dv.x, rv.y + dv.y, rv.z + dv.z, rv.w + dv.w, gamma, beta, tid, red, &o);
  u16 u[4] = { f2bf(o.x), f2bf(o.y), f2bf(o.z), f2bf(o.w) };
  *(uint2*)(outh + base + tid * 4) = *(const uint2*)u;
}

// LN2: sum = bf16 x1 + f32 y2 + colbias (bf2); -> f32 out (in-place ok)
__global__ __launch_bounds__(256) void ln2_kernel(const u16* __restrict__ r,
                                                  const float* dl,
                                                  const float* __restrict__ colbias,
                                                  const float* __restrict__ gamma,
                                                  const float* __restrict__ beta,
                                                  float* outf) {
  __shared__ float red[4];
  int row = blockIdx.x, tid = threadIdx.x;
  size_t base = (size_t)row * Dm;
  uint2 ru = *(const uint2*)(r + base + tid * 4);
  const u16* pu = (const u16*)&ru;
  float4 dv = *(const float4*)(dl + base + tid * 4);
  float4 bb = *(const float4*)(colbias + tid * 4);
  float4 o;
  ln_core(bf2f(pu[0]) + dv.x + bb.x, bf2f(pu[1]) + dv.y + bb.y,
          bf2f(pu[2]) + dv.z + bb.z, bf2f(pu[3]) + dv.w + bb.w,
          gamma, beta, tid, red, &o);
  *(float4*)(outf + base + tid * 4) = o;
}

// ---------------- launch ----------------
extern "C" void kernel_launch(void* const* d_in, const int* in_sizes, int n_in,
                              void* d_out, int out_size, void* d_ws, size_t ws_size,
                              hipStream_t stream) {
  const float* x         = (const float*)d_in[0];
  const float* in_proj_w = (const float*)d_in[1];
  const float* in_proj_b = (const float*)d_in[2];
  const float* out_w     = (const float*)d_in[3];
  const float* out_b     = (const float*)d_in[4];
  const float* gamma1    = (const float*)d_in[5];
  const float* beta1     = (const float*)d_in[6];
  const float* w1        = (const float*)d_in[7];
  const float* bf1       = (const float*)d_in[8];
  const float* w2        = (const float*)d_in[9];
  const float* bf2       = (const float*)d_in[10];
  const float* gamma2    = (const float*)d_in[11];
  const float* beta2     = (const float*)d_in[12];
  float* out = (float*)d_out;

  char* ws = (char*)d_ws;
  size_t off = 0;
  auto alloc = [&](size_t bytes) -> char* {
    char* p = ws + off;
    off += (bytes + 255) & ~(size_t)255;
    return p;
  };
  u16* wqkvh = (u16*)alloc((size_t)3 * Dm * Dm * 2);
  u16* owh   = (u16*)alloc((size_t)Dm * Dm * 2);
  u16* w1th  = (u16*)alloc((size_t)FFd * Dm * 2);
  u16* w2th  = (u16*)alloc((size_t)Dm * FFd * 2);
  u16* big   = (u16*)alloc((size_t)NTOK * FFd * 2);
  u16* x1h   = (u16*)alloc((size_t)NTOK * Dm * 2);
  u16* qkvh = big;
  u16* hh   = big;
  u16* xh   = (u16*)d_out;
  float* attnf = out;
  float* y2f   = out;

  cvt_f32_bf16<<<(long)NTOK * Dm / 1024, 256, 0, stream>>>(x, xh, (long)NTOK * Dm);
  cvt_f32_bf16<<<(long)3 * Dm * Dm / 1024, 256, 0, stream>>>(in_proj_w, wqkvh, (long)3 * Dm * Dm);
  cvt_f32_bf16<<<(long)Dm * Dm / 1024, 256, 0, stream>>>(out_w, owh, (long)Dm * Dm);
  transpose_f32_bf16<<<dim3(FFd / 32, Dm / 32), 256, 0, stream>>>(w1, w1th, Dm, FFd);
  transpose_f32_bf16<<<dim3(Dm / 32, FFd / 32), 256, 0, stream>>>(w2, w2th, FFd, Dm);

  // QKV projection: [16384,1024] x [3072,1024]^T -> bf16 [16384,3072]
  gemm8p<0, 1, 1><<<dim3(3 * Dm / 256, NTOK / 256), 512, 0, stream>>>(
      xh, Dm, wqkvh, in_proj_b, qkvh, NTOK, 3 * Dm, Dm);

  attn_mfma<<<Bsz * NC * Hh, 256, 0, stream>>>(qkvh);

  // out projection: attn-out (qkv cols 0..1023) x out_w^T -> f32
  gemm8p<0, 0, 1><<<dim3(Dm / 256, NTOK / 256), 512, 0, stream>>>(
      qkvh, 3 * Dm, owh, out_b, attnf, NTOK, Dm, Dm);

  ln1_kernel<<<NTOK, 256, 0, stream>>>(x, attnf, gamma1, beta1, x1h);

  // FFN1 + ReLU -> bf16 [16384,4096]
  gemm8p<1, 1, 1><<<dim3(FFd / 256, NTOK / 256), 512, 0, stream>>>(
      x1h, Dm, w1th, bf1, hh, NTOK, FFd, Dm);

  // FFN2 -> f32 (bias bf2 folded into LN2)
  gemm8p<0, 0, 0><<<dim3(Dm / 256, NTOK / 256), 512, 0, stream>>>(
      hh, FFd, w2th, (const float*)nullptr, y2f, NTOK, Dm, FFd);

  ln2_kernel<<<NTOK, 256, 0, stream>>>(x1h, y2f, bf2, gamma2, beta2, out);
}